// Round 1
// baseline (683.898 us; speedup 1.0000x reference)
//
#include <hip/hip_runtime.h>
#include <hip/hip_bf16.h>

// ScaledDotProductAttention: S = (Q K^T)/32 * mask (multiplicative!), attn = softmax(S),
// ctx = attn * K  (reference multiplies by KEY, not value).
// d_out = ctx (8*2048*1024 fp32) ++ attn (8*2048*2048 fp32). No d_ws usage.

typedef __attribute__((ext_vector_type(8))) short bf16x8;   // 8 bf16 = 4 VGPRs (guide §3)
typedef __attribute__((ext_vector_type(4))) float f32x4;

constexpr int BATCH = 8;
constexpr int LQ    = 2048;
constexpr int LKK   = 2048;
constexpr int DH    = 1024;
constexpr float SCALE = 0.03125f;   // 1/sqrt(1024)

constexpr int BM = 128, BN = 128, TK = 32;
constexpr int LDSS = 40;            // padded LDS row stride (elems): 80B rows keep b128 reads 16B-aligned, <=2-way banks

// round-half-up fp32->bf16 pair pack: 2 adds + 1 v_perm (tie bias ~2^-17, irrelevant here)
__device__ __forceinline__ unsigned pack_bf16x2(float x0, float x1) {
    unsigned a = __builtin_bit_cast(unsigned, x0) + 0x8000u;
    unsigned b = __builtin_bit_cast(unsigned, x1) + 0x8000u;
    return __builtin_amdgcn_perm(b, a, 0x07060302u);  // [b.hi16 : a.hi16]
}

// ---------------- GEMM1: S[b,q,k] = (Q[b,q,:] . K[b,k,:]) * SCALE * mask ----------------
__global__ __launch_bounds__(256, 2)
void qk_kernel(const float* __restrict__ Q, const float* __restrict__ K,
               const float* __restrict__ M, float* __restrict__ S) {
    __shared__ unsigned short lA[BM * LDSS];  // Q tile [128 q][32 k] bf16
    __shared__ unsigned short lB[BN * LDSS];  // K tile [128 n][32 k] bf16 (already K-major: B^T gemm)

    const int b  = blockIdx.z;
    const int q0 = blockIdx.y * BM;
    const int n0 = blockIdx.x * BN;
    const float* Qb = Q + (size_t)b * LQ  * DH + (size_t)q0 * DH;
    const float* Kb = K + (size_t)b * LKK * DH + (size_t)n0 * DH;

    const int tid  = threadIdx.x;
    const int lane = tid & 63;
    const int wid  = tid >> 6;
    const int wm   = (wid & 1) * 64;
    const int wn   = (wid >> 1) * 64;
    const int lrow = lane & 15;
    const int quad = lane >> 4;

    f32x4 acc[4][4];
#pragma unroll
    for (int i = 0; i < 4; ++i)
#pragma unroll
        for (int j = 0; j < 4; ++j) acc[i][j] = (f32x4){0.f, 0.f, 0.f, 0.f};

    const int srow = tid >> 3;          // 0..31
    const int skq  = (tid & 7) << 2;    // 0,4,..,28

    for (int k0 = 0; k0 < DH; k0 += TK) {
        __syncthreads();
#pragma unroll
        for (int i = 0; i < 4; ++i) {
            const int row = i * 32 + srow;
            const f32x4 va = *(const f32x4*)(Qb + (size_t)row * DH + k0 + skq);
            const f32x4 vb = *(const f32x4*)(Kb + (size_t)row * DH + k0 + skq);
            unsigned* pa = (unsigned*)&lA[row * LDSS + skq];
            pa[0] = pack_bf16x2(va[0], va[1]);
            pa[1] = pack_bf16x2(va[2], va[3]);
            unsigned* pb = (unsigned*)&lB[row * LDSS + skq];
            pb[0] = pack_bf16x2(vb[0], vb[1]);
            pb[1] = pack_bf16x2(vb[2], vb[3]);
        }
        __syncthreads();

        bf16x8 af[4], bfr[4];
#pragma unroll
        for (int i = 0; i < 4; ++i) {
            af[i]  = *(const bf16x8*)&lA[(wm + i * 16 + lrow) * LDSS + quad * 8];
            bfr[i] = *(const bf16x8*)&lB[(wn + i * 16 + lrow) * LDSS + quad * 8];
        }
#pragma unroll
        for (int i = 0; i < 4; ++i)
#pragma unroll
            for (int j = 0; j < 4; ++j)
                acc[i][j] = __builtin_amdgcn_mfma_f32_16x16x32_bf16(af[i], bfr[j], acc[i][j], 0, 0, 0);
    }

    // epilogue: C/D layout col=lane&15, row=quad*4+r (verified m89/m91)
    const size_t base = (size_t)b * LQ * LKK;
#pragma unroll
    for (int i = 0; i < 4; ++i) {
#pragma unroll
        for (int r = 0; r < 4; ++r) {
            const int row = q0 + wm + i * 16 + quad * 4 + r;
            const size_t rbase = base + (size_t)row * LKK;
#pragma unroll
            for (int j = 0; j < 4; ++j) {
                const int col = n0 + wn + j * 16 + lrow;
                S[rbase + col] = acc[i][j][r] * SCALE * M[rbase + col];
            }
        }
    }
}

// ---------------- softmax over rows of S (in place), masked entries are 0 (exp(0) counts!) ----
__global__ __launch_bounds__(256)
void softmax_kernel(float* __restrict__ A) {
    float* p = A + (size_t)blockIdx.x * LKK;
    const int tid  = threadIdx.x;
    const int lane = tid & 63;
    const int wid  = tid >> 6;

    f32x4 v0 = *(const f32x4*)(p + tid * 8);
    f32x4 v1 = *(const f32x4*)(p + tid * 8 + 4);

    float m = v0[0];
#pragma unroll
    for (int i = 1; i < 4; ++i) m = fmaxf(m, v0[i]);
#pragma unroll
    for (int i = 0; i < 4; ++i) m = fmaxf(m, v1[i]);
#pragma unroll
    for (int o = 32; o >= 1; o >>= 1) m = fmaxf(m, __shfl_xor(m, o, 64));

    __shared__ float red[8];
    if (lane == 0) red[wid] = m;
    __syncthreads();
    m = fmaxf(fmaxf(red[0], red[1]), fmaxf(red[2], red[3]));

    float s = 0.f;
    f32x4 e0, e1;
#pragma unroll
    for (int i = 0; i < 4; ++i) { e0[i] = __expf(v0[i] - m); s += e0[i]; }
#pragma unroll
    for (int i = 0; i < 4; ++i) { e1[i] = __expf(v1[i] - m); s += e1[i]; }
#pragma unroll
    for (int o = 32; o >= 1; o >>= 1) s += __shfl_xor(s, o, 64);
    if (lane == 0) red[4 + wid] = s;
    __syncthreads();
    const float inv = 1.f / (red[4] + red[5] + red[6] + red[7]);

#pragma unroll
    for (int i = 0; i < 4; ++i) { e0[i] *= inv; e1[i] *= inv; }
    *(f32x4*)(p + tid * 8)     = e0;
    *(f32x4*)(p + tid * 8 + 4) = e1;
}

// ---------------- GEMM2: ctx[b,q,d] = sum_k attn[b,q,k] * K[b,k,d] ----------------
__global__ __launch_bounds__(256, 2)
void pk_kernel(const float* __restrict__ P, const float* __restrict__ K,
               float* __restrict__ C) {
    __shared__ unsigned short lA[BM * LDSS];  // attn tile [128 q][32 k]
    __shared__ unsigned short lB[BN * LDSS];  // K^T tile  [128 d][32 k]  (transposed on store)

    const int b  = blockIdx.z;
    const int q0 = blockIdx.y * BM;
    const int n0 = blockIdx.x * BN;   // d offset
    const float* Pb = P + (size_t)b * LQ * LKK + (size_t)q0 * LKK;
    const float* Kb = K + (size_t)b * LKK * DH;

    const int tid  = threadIdx.x;
    const int lane = tid & 63;
    const int wid  = tid >> 6;
    const int wm   = (wid & 1) * 64;
    const int wn   = (wid >> 1) * 64;
    const int lrow = lane & 15;
    const int quad = lane >> 4;

    f32x4 acc[4][4];
#pragma unroll
    for (int i = 0; i < 4; ++i)
#pragma unroll
        for (int j = 0; j < 4; ++j) acc[i][j] = (f32x4){0.f, 0.f, 0.f, 0.f};

    const int srow = tid >> 3;          // A staging: 0..31
    const int skq  = (tid & 7) << 2;
    const int tdb  = tid >> 3;          // B staging: d-block 0..31
    const int tkb  = tid & 7;           // B staging: k-block 0..7

    for (int k0 = 0; k0 < LKK; k0 += TK) {
        __syncthreads();
        // A: attn rows, contiguous k, fp32 -> bf16
#pragma unroll
        for (int i = 0; i < 4; ++i) {
            const int row = i * 32 + srow;
            const f32x4 va = *(const f32x4*)(Pb + (size_t)row * LKK + k0 + skq);
            unsigned* pa = (unsigned*)&lA[row * LDSS + skq];
            pa[0] = pack_bf16x2(va[0], va[1]);
            pa[1] = pack_bf16x2(va[2], va[3]);
        }
        // B: K tile 32k x 128d, 4x4 register-block transpose -> lB[d][k]
        f32x4 rk[4];
#pragma unroll
        for (int j = 0; j < 4; ++j)
            rk[j] = *(const f32x4*)(Kb + (size_t)(k0 + tkb * 4 + j) * DH + n0 + tdb * 4);
#pragma unroll
        for (int c = 0; c < 4; ++c) {
            unsigned* pb = (unsigned*)&lB[(tdb * 4 + c) * LDSS + tkb * 4];
            pb[0] = pack_bf16x2(rk[0][c], rk[1][c]);
            pb[1] = pack_bf16x2(rk[2][c], rk[3][c]);
        }
        __syncthreads();

        bf16x8 af[4], bfr[4];
#pragma unroll
        for (int i = 0; i < 4; ++i) {
            af[i]  = *(const bf16x8*)&lA[(wm + i * 16 + lrow) * LDSS + quad * 8];
            bfr[i] = *(const bf16x8*)&lB[(wn + i * 16 + lrow) * LDSS + quad * 8];
        }
#pragma unroll
        for (int i = 0; i < 4; ++i)
#pragma unroll
            for (int j = 0; j < 4; ++j)
                acc[i][j] = __builtin_amdgcn_mfma_f32_16x16x32_bf16(af[i], bfr[j], acc[i][j], 0, 0, 0);
    }

    const size_t cb = (size_t)b * LQ * DH;
#pragma unroll
    for (int i = 0; i < 4; ++i) {
#pragma unroll
        for (int r = 0; r < 4; ++r) {
            const int row = q0 + wm + i * 16 + quad * 4 + r;
            const size_t rbase = cb + (size_t)row * DH;
#pragma unroll
            for (int j = 0; j < 4; ++j) {
                const int col = n0 + wn + j * 16 + lrow;
                C[rbase + col] = acc[i][j][r];
            }
        }
    }
}

extern "C" void kernel_launch(void* const* d_in, const int* in_sizes, int n_in,
                              void* d_out, int out_size, void* d_ws, size_t ws_size,
                              hipStream_t stream) {
    const float* Q = (const float*)d_in[0];
    const float* K = (const float*)d_in[1];
    const float* M = (const float*)d_in[2];
    float* ctx  = (float*)d_out;
    float* attn = ctx + (size_t)BATCH * LQ * DH;   // outputs concatenated: ctx then attn

    qk_kernel<<<dim3(LKK / BN, LQ / BM, BATCH), 256, 0, stream>>>(Q, K, M, attn);
    softmax_kernel<<<dim3(BATCH * LQ), 256, 0, stream>>>(attn);
    pk_kernel<<<dim3(DH / BN, LQ / BM, BATCH), 256, 0, stream>>>(attn, K, ctx);
}

// Round 2
// 660.660 us; speedup vs baseline: 1.0352x; 1.0352x over previous
//
#include <hip/hip_runtime.h>
#include <hip/hip_bf16.h>

// S = (Q K^T)/32 * mask (multiplicative), attn = softmax(S), ctx = attn * K.
// d_out = ctx (8*2048*1024 f32) ++ attn (8*2048*2048 f32).
// Strategy R2: pre-convert Q,K -> bf16 into the ctx region of d_out (dead until pk),
// K^T bf16 + attn bf16 into d_ws (runtime-checked, fallback to R1 pk), then both
// GEMMs use m97-style global_load_lds dwordx4 staging with NO in-loop conversion.

typedef __attribute__((ext_vector_type(8))) short bf16x8;
typedef __attribute__((ext_vector_type(4))) float f32x4;
typedef __attribute__((ext_vector_type(4))) unsigned u32x4;
typedef __attribute__((ext_vector_type(2))) unsigned u32x2;

constexpr int BATCH = 8;
constexpr int LQ    = 2048;
constexpr int LKK   = 2048;
constexpr int DH    = 1024;
constexpr float SCALE = 0.03125f;   // 1/sqrt(1024)

constexpr int BM = 128, BN = 128, TK = 32;

#define GAS(p) ((const __attribute__((address_space(1))) void*)(p))
#define LAS(p) ((__attribute__((address_space(3))) void*)(p))

// round-half-up fp32->bf16 pair pack (2 adds + v_perm)
__device__ __forceinline__ unsigned pack_bf16x2(float x0, float x1) {
    unsigned a = __builtin_bit_cast(unsigned, x0) + 0x8000u;
    unsigned b = __builtin_bit_cast(unsigned, x1) + 0x8000u;
    return __builtin_amdgcn_perm(b, a, 0x07060302u);  // mem order: x0.hi16, x1.hi16
}

// ---------------- prep: Q,K fp32 -> bf16 (row-major, same layout) ----------------
__global__ __launch_bounds__(256)
void cvt_kernel(const float* __restrict__ Q, const float* __restrict__ K,
                unsigned short* __restrict__ Qb, unsigned short* __restrict__ Kb) {
    const int bid = blockIdx.x;
    const float* src; unsigned short* dst; size_t off;
    if (bid < 4096) { src = Q; dst = Qb; off = (size_t)bid * 4096; }
    else            { src = K; dst = Kb; off = (size_t)(bid - 4096) * 4096; }
    off += (size_t)threadIdx.x * 16;
    const f32x4 a = *(const f32x4*)(src + off);
    const f32x4 b = *(const f32x4*)(src + off + 4);
    const f32x4 c = *(const f32x4*)(src + off + 8);
    const f32x4 d = *(const f32x4*)(src + off + 12);
    u32x4 v0, v1;
    v0[0] = pack_bf16x2(a[0], a[1]); v0[1] = pack_bf16x2(a[2], a[3]);
    v0[2] = pack_bf16x2(b[0], b[1]); v0[3] = pack_bf16x2(b[2], b[3]);
    v1[0] = pack_bf16x2(c[0], c[1]); v1[1] = pack_bf16x2(c[2], c[3]);
    v1[2] = pack_bf16x2(d[0], d[1]); v1[3] = pack_bf16x2(d[2], d[3]);
    *(u32x4*)(dst + off)     = v0;
    *(u32x4*)(dst + off + 8) = v1;
}

// ---------------- prep: K fp32 -> K^T bf16, KT[b][d][k] (register 4x4 transpose) ----
__global__ __launch_bounds__(256)
void kt_kernel(const float* __restrict__ K, unsigned short* __restrict__ KT) {
    const int b  = blockIdx.z;
    const int k0 = blockIdx.y * 64;
    const int d0 = blockIdx.x * 64;
    const int t  = threadIdx.x;
    const int k4 = (t >> 4) * 4;   // 0..60
    const int d4 = (t & 15) * 4;   // 0..60 (consecutive lanes -> consecutive d: coalesced reads)
    f32x4 rk[4];
    const float* Kp = K + ((size_t)b * LKK + k0 + k4) * DH + d0 + d4;
#pragma unroll
    for (int j = 0; j < 4; ++j) rk[j] = *(const f32x4*)(Kp + (size_t)j * DH);
    unsigned short* Tp = KT + ((size_t)b * DH + d0 + d4) * LKK + k0 + k4;
#pragma unroll
    for (int c = 0; c < 4; ++c) {
        u32x2 w;
        w[0] = pack_bf16x2(rk[0][c], rk[1][c]);
        w[1] = pack_bf16x2(rk[2][c], rk[3][c]);
        *(u32x2*)(Tp + (size_t)c * LKK) = w;
    }
}

// ---------------- GEMM1: S[b,q,n] = (Qb[q,:] . Kb[n,:]) * SCALE * M ----------------
// m97 structure: global_load_lds dwordx4 staging of bf16 tiles, 16x16x32 MFMA.
__global__ __launch_bounds__(256)
void qk_fast(const unsigned short* __restrict__ Qb, const unsigned short* __restrict__ Kb,
             const float* __restrict__ M, float* __restrict__ S) {
    __shared__ unsigned short lA[BM * TK];   // [128 q][32 k] bf16, packed rows (64 B)
    __shared__ unsigned short lB[BN * TK];

    const int b  = blockIdx.z;
    const int q0 = blockIdx.y * BM;
    const int n0 = blockIdx.x * BN;
    const unsigned short* Ab = Qb + ((size_t)b * LQ  + q0) * DH;
    const unsigned short* Bb = Kb + ((size_t)b * LKK + n0) * DH;

    const int tid  = threadIdx.x;
    const int lane = tid & 63;
    const int wid  = tid >> 6;
    const int wm   = (wid & 1) * 64;
    const int wn   = (wid >> 1) * 64;
    const int lrow = lane & 15;
    const int quad = lane >> 4;
    const int l4   = lane >> 2;     // staging sub-row 0..15
    const int lb   = lane & 3;      // staging 16B chunk within 64B row

    f32x4 acc[4][4];
#pragma unroll
    for (int i = 0; i < 4; ++i)
#pragma unroll
        for (int j = 0; j < 4; ++j) acc[i][j] = (f32x4){0.f, 0.f, 0.f, 0.f};

    for (int k0 = 0; k0 < DH; k0 += TK) {
        __syncthreads();
#pragma unroll
        for (int n = 0; n < 2; ++n) {
            const int row = wid * 32 + n * 16 + l4;           // 0..127
            __builtin_amdgcn_global_load_lds(GAS(Ab + (size_t)row * DH + k0 + lb * 8),
                                             LAS(&lA[(wid * 2 + n) * 512]), 16, 0, 0);
            __builtin_amdgcn_global_load_lds(GAS(Bb + (size_t)row * DH + k0 + lb * 8),
                                             LAS(&lB[(wid * 2 + n) * 512]), 16, 0, 0);
        }
        __syncthreads();

        bf16x8 af[4], bfr[4];
#pragma unroll
        for (int i = 0; i < 4; ++i) {
            af[i]  = *(const bf16x8*)&lA[(wm + i * 16 + lrow) * TK + quad * 8];
            bfr[i] = *(const bf16x8*)&lB[(wn + i * 16 + lrow) * TK + quad * 8];
        }
#pragma unroll
        for (int i = 0; i < 4; ++i)
#pragma unroll
            for (int j = 0; j < 4; ++j)
                acc[i][j] = __builtin_amdgcn_mfma_f32_16x16x32_bf16(af[i], bfr[j], acc[i][j], 0, 0, 0);
    }

    // C/D layout: col=lane&15, row=quad*4+r (m89/m91)
    const size_t base = (size_t)b * LQ * LKK;
#pragma unroll
    for (int i = 0; i < 4; ++i) {
#pragma unroll
        for (int r = 0; r < 4; ++r) {
            const int row = q0 + wm + i * 16 + quad * 4 + r;
            const size_t rbase = base + (size_t)row * LKK;
#pragma unroll
            for (int j = 0; j < 4; ++j) {
                const int col = n0 + wn + j * 16 + lrow;
                S[rbase + col] = acc[i][j][r] * SCALE * M[rbase + col];
            }
        }
    }
}

// ---------------- softmax rows of S in place; optional bf16 copy for pk_fast -------
__global__ __launch_bounds__(256)
void softmax_kernel(float* __restrict__ A, unsigned short* __restrict__ ab) {
    float* p = A + (size_t)blockIdx.x * LKK;
    const int tid  = threadIdx.x;
    const int lane = tid & 63;
    const int wid  = tid >> 6;

    f32x4 v0 = *(const f32x4*)(p + tid * 8);
    f32x4 v1 = *(const f32x4*)(p + tid * 8 + 4);

    float m = v0[0];
#pragma unroll
    for (int i = 1; i < 4; ++i) m = fmaxf(m, v0[i]);
#pragma unroll
    for (int i = 0; i < 4; ++i) m = fmaxf(m, v1[i]);
#pragma unroll
    for (int o = 32; o >= 1; o >>= 1) m = fmaxf(m, __shfl_xor(m, o, 64));

    __shared__ float red[8];
    if (lane == 0) red[wid] = m;
    __syncthreads();
    m = fmaxf(fmaxf(red[0], red[1]), fmaxf(red[2], red[3]));

    float s = 0.f;
    f32x4 e0, e1;
#pragma unroll
    for (int i = 0; i < 4; ++i) { e0[i] = __expf(v0[i] - m); s += e0[i]; }
#pragma unroll
    for (int i = 0; i < 4; ++i) { e1[i] = __expf(v1[i] - m); s += e1[i]; }
#pragma unroll
    for (int o = 32; o >= 1; o >>= 1) s += __shfl_xor(s, o, 64);
    if (lane == 0) red[4 + wid] = s;
    __syncthreads();
    const float inv = 1.f / (red[4] + red[5] + red[6] + red[7]);

#pragma unroll
    for (int i = 0; i < 4; ++i) { e0[i] *= inv; e1[i] *= inv; }
    *(f32x4*)(p + tid * 8)     = e0;
    *(f32x4*)(p + tid * 8 + 4) = e1;

    if (ab) {
        u32x4 w;
        w[0] = pack_bf16x2(e0[0], e0[1]); w[1] = pack_bf16x2(e0[2], e0[3]);
        w[2] = pack_bf16x2(e1[0], e1[1]); w[3] = pack_bf16x2(e1[2], e1[3]);
        *(u32x4*)(ab + (size_t)blockIdx.x * LKK + tid * 8) = w;
    }
}

// ---------------- GEMM2 fast: ctx = attn_bf * KT_bf (both pre-packed bf16) ---------
__global__ __launch_bounds__(256)
void pk_fast(const unsigned short* __restrict__ Pb, const unsigned short* __restrict__ KT,
             float* __restrict__ C) {
    __shared__ unsigned short lA[BM * TK];
    __shared__ unsigned short lB[BN * TK];

    const int b  = blockIdx.z;
    const int q0 = blockIdx.y * BM;
    const int n0 = blockIdx.x * BN;   // d offset
    const unsigned short* Ab = Pb + ((size_t)b * LQ + q0) * LKK;
    const unsigned short* Bb = KT + ((size_t)b * DH + n0) * LKK;

    const int tid  = threadIdx.x;
    const int lane = tid & 63;
    const int wid  = tid >> 6;
    const int wm   = (wid & 1) * 64;
    const int wn   = (wid >> 1) * 64;
    const int lrow = lane & 15;
    const int quad = lane >> 4;
    const int l4   = lane >> 2;
    const int lb   = lane & 3;

    f32x4 acc[4][4];
#pragma unroll
    for (int i = 0; i < 4; ++i)
#pragma unroll
        for (int j = 0; j < 4; ++j) acc[i][j] = (f32x4){0.f, 0.f, 0.f, 0.f};

    for (int k0 = 0; k0 < LKK; k0 += TK) {
        __syncthreads();
#pragma unroll
        for (int n = 0; n < 2; ++n) {
            const int row = wid * 32 + n * 16 + l4;
            __builtin_amdgcn_global_load_lds(GAS(Ab + (size_t)row * LKK + k0 + lb * 8),
                                             LAS(&lA[(wid * 2 + n) * 512]), 16, 0, 0);
            __builtin_amdgcn_global_load_lds(GAS(Bb + (size_t)row * LKK + k0 + lb * 8),
                                             LAS(&lB[(wid * 2 + n) * 512]), 16, 0, 0);
        }
        __syncthreads();

        bf16x8 af[4], bfr[4];
#pragma unroll
        for (int i = 0; i < 4; ++i) {
            af[i]  = *(const bf16x8*)&lA[(wm + i * 16 + lrow) * TK + quad * 8];
            bfr[i] = *(const bf16x8*)&lB[(wn + i * 16 + lrow) * TK + quad * 8];
        }
#pragma unroll
        for (int i = 0; i < 4; ++i)
#pragma unroll
            for (int j = 0; j < 4; ++j)
                acc[i][j] = __builtin_amdgcn_mfma_f32_16x16x32_bf16(af[i], bfr[j], acc[i][j], 0, 0, 0);
    }

    const size_t cb = (size_t)b * LQ * DH;
#pragma unroll
    for (int i = 0; i < 4; ++i) {
#pragma unroll
        for (int r = 0; r < 4; ++r) {
            const int row = q0 + wm + i * 16 + quad * 4 + r;
            const size_t rbase = cb + (size_t)row * DH;
#pragma unroll
            for (int j = 0; j < 4; ++j)
                C[rbase + n0 + wn + j * 16 + lrow] = acc[i][j][r];
        }
    }
}

// ---------------- GEMM2 fallback (R1): inline fp32->bf16 conversion ----------------
constexpr int LDSS = 40;
__global__ __launch_bounds__(256, 2)
void pk_kernel(const float* __restrict__ P, const float* __restrict__ K,
               float* __restrict__ C) {
    __shared__ unsigned short lA[BM * LDSS];
    __shared__ unsigned short lB[BN * LDSS];

    const int b  = blockIdx.z;
    const int q0 = blockIdx.y * BM;
    const int n0 = blockIdx.x * BN;
    const float* Pp = P + (size_t)b * LQ * LKK + (size_t)q0 * LKK;
    const float* Kb = K + (size_t)b * LKK * DH;

    const int tid  = threadIdx.x;
    const int lane = tid & 63;
    const int wid  = tid >> 6;
    const int wm   = (wid & 1) * 64;
    const int wn   = (wid >> 1) * 64;
    const int lrow = lane & 15;
    const int quad = lane >> 4;

    f32x4 acc[4][4];
#pragma unroll
    for (int i = 0; i < 4; ++i)
#pragma unroll
        for (int j = 0; j < 4; ++j) acc[i][j] = (f32x4){0.f, 0.f, 0.f, 0.f};

    const int srow = tid >> 3;
    const int skq  = (tid & 7) << 2;
    const int tdb  = tid >> 3;
    const int tkb  = tid & 7;

    for (int k0 = 0; k0 < LKK; k0 += TK) {
        __syncthreads();
#pragma unroll
        for (int i = 0; i < 4; ++i) {
            const int row = i * 32 + srow;
            const f32x4 va = *(const f32x4*)(Pp + (size_t)row * LKK + k0 + skq);
            unsigned* pa = (unsigned*)&lA[row * LDSS + skq];
            pa[0] = pack_bf16x2(va[0], va[1]);
            pa[1] = pack_bf16x2(va[2], va[3]);
        }
        f32x4 rk[4];
#pragma unroll
        for (int j = 0; j < 4; ++j)
            rk[j] = *(const f32x4*)(Kb + (size_t)(k0 + tkb * 4 + j) * DH + n0 + tdb * 4);
#pragma unroll
        for (int c = 0; c < 4; ++c) {
            unsigned* pb = (unsigned*)&lB[(tdb * 4 + c) * LDSS + tkb * 4];
            pb[0] = pack_bf16x2(rk[0][c], rk[1][c]);
            pb[1] = pack_bf16x2(rk[2][c], rk[3][c]);
        }
        __syncthreads();

        bf16x8 af[4], bfr[4];
#pragma unroll
        for (int i = 0; i < 4; ++i) {
            af[i]  = *(const bf16x8*)&lA[(wm + i * 16 + lrow) * LDSS + quad * 8];
            bfr[i] = *(const bf16x8*)&lB[(wn + i * 16 + lrow) * LDSS + quad * 8];
        }
#pragma unroll
        for (int i = 0; i < 4; ++i)
#pragma unroll
            for (int j = 0; j < 4; ++j)
                acc[i][j] = __builtin_amdgcn_mfma_f32_16x16x32_bf16(af[i], bfr[j], acc[i][j], 0, 0, 0);
    }

    const size_t cb = (size_t)b * LQ * DH;
#pragma unroll
    for (int i = 0; i < 4; ++i) {
#pragma unroll
        for (int r = 0; r < 4; ++r) {
            const int row = q0 + wm + i * 16 + quad * 4 + r;
            const size_t rbase = cb + (size_t)row * DH;
#pragma unroll
            for (int j = 0; j < 4; ++j)
                C[rbase + n0 + wn + j * 16 + lrow] = acc[i][j][r];
        }
    }
}

extern "C" void kernel_launch(void* const* d_in, const int* in_sizes, int n_in,
                              void* d_out, int out_size, void* d_ws, size_t ws_size,
                              hipStream_t stream) {
    const float* Q = (const float*)d_in[0];
    const float* K = (const float*)d_in[1];
    const float* M = (const float*)d_in[2];

    constexpr size_t QEL  = (size_t)BATCH * LQ * DH;    // 16,777,216 (ctx elems)
    constexpr size_t AEL  = (size_t)BATCH * LQ * LKK;   // 33,554,432 (attn elems)
    constexpr size_t KTEL = (size_t)BATCH * DH * LKK;   // 16,777,216

    float* ctx  = (float*)d_out;
    float* attn = ctx + QEL;

    // bf16 Q/K scratch inside the (not-yet-written) ctx region: 2*QEL*2B == QEL*4B exactly.
    unsigned short* Qb = (unsigned short*)ctx;
    unsigned short* Kb = Qb + QEL;

    const bool wsOK = ws_size >= (KTEL + AEL) * sizeof(unsigned short);
    unsigned short* KT = (unsigned short*)d_ws;
    unsigned short* ab = KT + KTEL;

    cvt_kernel<<<dim3(8192), 256, 0, stream>>>(Q, K, Qb, Kb);
    if (wsOK)
        kt_kernel<<<dim3(DH / 64, LKK / 64, BATCH), 256, 0, stream>>>(K, KT);
    qk_fast<<<dim3(LKK / BN, LQ / BM, BATCH), 256, 0, stream>>>(Qb, Kb, M, attn);
    softmax_kernel<<<dim3(BATCH * LQ), 256, 0, stream>>>(attn, wsOK ? ab : nullptr);
    if (wsOK)
        pk_fast<<<dim3(DH / BN, LQ / BM, BATCH), 256, 0, stream>>>(ab, KT, ctx);
    else
        pk_kernel<<<dim3(DH / BN, LQ / BM, BATCH), 256, 0, stream>>>(attn, K, ctx);
}